// Round 6
// baseline (88.502 us; speedup 1.0000x reference)
//
#include <hip/hip_runtime.h>
#include <hip/hip_bf16.h>
#include <stdint.h>

#define SLOPE 0.2f

typedef short s16x8 __attribute__((ext_vector_type(8)));
typedef float f32x4 __attribute__((ext_vector_type(4)));

// gfx950 native packed f32->bf16 (RNE), one VALU op for two converts.
__device__ __forceinline__ uint32_t pk_bf16(float lo, float hi) {
    uint32_t r;
    asm("v_cvt_pk_bf16_f32 %0, %1, %2" : "=v"(r) : "v"(lo), "v"(hi));
    return r;
}

// ---------------------------------------------------------------------------
// Round-13: main_kernel reverted to round-11 exactly (best measured: 87.50 us;
// round-12's K=128 step was neutral-to-negative and is dropped).
//   bx   0..127 : GEMM 64x64 tile, 16 iters x K=64, distance-2 B prefetch
//   bx 128..255 : s_e edge scores (2 threads/edge)
//   bx 256..271 : row_start scans
// Single change this round: attn_kernel restructured to one row-unit per
// WAVE (256 blocks x 4 waves, ZERO __syncthreads; wave-synchronous LDS only).
// All reduction trees / accumulation orders identical -> bitwise-same output.
// ---------------------------------------------------------------------------
__global__ __launch_bounds__(256)
void main_kernel(const float* __restrict__ hmat,       // [1024][1024]
                 const float* __restrict__ adj,        // [16][64][64]
                 const float* __restrict__ edge_attr,  // [16384][128]
                 const float* __restrict__ W_node,     // [1024][512]
                 const float* __restrict__ W_edge,     // [128][512]
                 const float* __restrict__ w_attn,     // [192]
                 float* __restrict__ g,                // [1024][512]
                 float* __restrict__ s_e,              // [16384][8]
                 float* __restrict__ s_i,              // [1024][8]
                 float* __restrict__ s_j,              // [1024][8]
                 int* __restrict__ row_start)          // [1024]
{
    __shared__ __align__(16) char U[20480];
    unsigned short* Bs = (unsigned short*)U;   // [4 slots][64][40] = 20480 B
    float* wvs = (float*)U;                    // edge role overlay (4 KB)

    int bx = blockIdx.x, tid = threadIdx.x;

    if (bx < 128) {
        // ================= GEMM role (round-11 verbatim) =====================
        int head = bx & 7, mt = bx >> 3;
        int n0 = head * 64, m0 = mt * 64;
        int wave = tid >> 6, lane = tid & 63;
        int l15 = lane & 15, quad = lane >> 4;
        int wv16 = wave * 16;

        int kp = tid >> 4, nq = tid & 15;      // B staging (transpose)

        const float* aFrag  = hmat + (size_t)(m0 + wv16 + l15) * 1024 + quad * 8;
        const float* bpBase = W_node + (size_t)(2 * kp) * 512 + n0 + nq * 4;

        f32x4 acc[4];
        #pragma unroll
        for (int i = 0; i < 4; ++i) acc[i] = (f32x4){0.f, 0.f, 0.f, 0.f};

        float4 a0, a1, a2, a3;                 // A regs, tile `it`
        float4 b00, b01, b10, b11;             // B regs, tile `it+2` in flight

        // ---- prologue: stage tile 0 into slots 0/1; load tile-1 B regs -----
        b00 = *(const float4*)(bpBase);
        b01 = *(const float4*)(bpBase + 512);
        b10 = *(const float4*)(bpBase + 32 * 512);
        b11 = *(const float4*)(bpBase + 33 * 512);
        {
            const float* q0 = &b00.x; const float* q1 = &b01.x;
            const float* q2 = &b10.x; const float* q3 = &b11.x;
            #pragma unroll
            for (int u = 0; u < 4; ++u) {
                *(uint32_t*)&Bs[(0 * 64 + nq * 4 + u) * 40 + 2 * kp] = pk_bf16(q0[u], q1[u]);
                *(uint32_t*)&Bs[(1 * 64 + nq * 4 + u) * 40 + 2 * kp] = pk_bf16(q2[u], q3[u]);
            }
        }
        {   // B regs <- tile 1
            const float* bp = bpBase + (size_t)64 * 512;
            b00 = *(const float4*)bp;
            b01 = *(const float4*)(bp + 512);
            b10 = *(const float4*)(bp + 32 * 512);
            b11 = *(const float4*)(bp + 33 * 512);
        }
        a0 = *(const float4*)(aFrag);
        a1 = *(const float4*)(aFrag + 4);
        a2 = *(const float4*)(aFrag + 32);
        a3 = *(const float4*)(aFrag + 36);
        __syncthreads();

        // ---- main loop: 16 iters of K=64, unrolled x2 for static buf parity
        #define GITER(IT, BUF, NOT_LAST, HAS_PF2)                              \
        {                                                                      \
            union { s16x8 v; uint32_t w[4]; } A0, A1;                          \
            A0.w[0] = pk_bf16(a0.x, a0.y); A0.w[1] = pk_bf16(a0.z, a0.w);      \
            A0.w[2] = pk_bf16(a1.x, a1.y); A0.w[3] = pk_bf16(a1.z, a1.w);      \
            A1.w[0] = pk_bf16(a2.x, a2.y); A1.w[1] = pk_bf16(a2.z, a2.w);      \
            A1.w[2] = pk_bf16(a3.x, a3.y); A1.w[3] = pk_bf16(a3.z, a3.w);      \
            if (NOT_LAST) {                                                    \
                const float* ap = aFrag + ((IT) + 1) * 64;                     \
                a0 = *(const float4*)ap;        a1 = *(const float4*)(ap + 4); \
                a2 = *(const float4*)(ap + 32); a3 = *(const float4*)(ap + 36);\
            }                                                                  \
            {                                                                  \
                s16x8 af = A0.v;                                               \
                _Pragma("unroll")                                              \
                for (int nt = 0; nt < 4; ++nt) {                               \
                    s16x8 bf = *(const s16x8*)&Bs[(((BUF)*2 + 0) * 64 + nt * 16 + l15) * 40 + quad * 8]; \
                    acc[nt] = __builtin_amdgcn_mfma_f32_16x16x32_bf16(af, bf, acc[nt], 0, 0, 0); \
                }                                                              \
            }                                                                  \
            {                                                                  \
                s16x8 af = A1.v;                                               \
                _Pragma("unroll")                                              \
                for (int nt = 0; nt < 4; ++nt) {                               \
                    s16x8 bf = *(const s16x8*)&Bs[(((BUF)*2 + 1) * 64 + nt * 16 + l15) * 40 + quad * 8]; \
                    acc[nt] = __builtin_amdgcn_mfma_f32_16x16x32_bf16(af, bf, acc[nt], 0, 0, 0); \
                }                                                              \
            }                                                                  \
            if (NOT_LAST) {   /* stage tile IT+1 (regs) into slots (BUF^1)*2 */\
                int sb = ((BUF) ^ 1) * 2;                                      \
                const float* q0 = &b00.x; const float* q1 = &b01.x;            \
                const float* q2 = &b10.x; const float* q3 = &b11.x;            \
                _Pragma("unroll")                                              \
                for (int u = 0; u < 4; ++u) {                                  \
                    *(uint32_t*)&Bs[((sb + 0) * 64 + nq * 4 + u) * 40 + 2 * kp] = pk_bf16(q0[u], q1[u]); \
                    *(uint32_t*)&Bs[((sb + 1) * 64 + nq * 4 + u) * 40 + 2 * kp] = pk_bf16(q2[u], q3[u]); \
                }                                                              \
            }                                                                  \
            if (HAS_PF2) {    /* B regs <- tile IT+2 */                        \
                const float* bp = bpBase + (size_t)(((IT) + 2) * 64) * 512;    \
                b00 = *(const float4*)bp;                                      \
                b01 = *(const float4*)(bp + 512);                              \
                b10 = *(const float4*)(bp + 32 * 512);                         \
                b11 = *(const float4*)(bp + 33 * 512);                         \
            }                                                                  \
            if (NOT_LAST) __syncthreads();                                     \
        }

        for (int ii = 0; ii < 8; ++ii) {
            int it = 2 * ii;
            GITER(it,     0, true,           it + 2 < 16);
            GITER(it + 1, 1, it + 1 < 15,    it + 3 < 16);
        }
        #undef GITER

        // ============ epilogue (round-4 verbatim: g + fused s_i/s_j) =========
        float wi[4], wj[4];
        #pragma unroll
        for (int nt = 0; nt < 4; ++nt) {
            wi[nt] = w_attn[nt * 16 + l15];
            wj[nt] = w_attn[64 + nt * 16 + l15];
        }
        float pi[4], pj[4];
        #pragma unroll
        for (int reg = 0; reg < 4; ++reg) { pi[reg] = 0.f; pj[reg] = 0.f; }
        #pragma unroll
        for (int nt = 0; nt < 4; ++nt) {
            #pragma unroll
            for (int reg = 0; reg < 4; ++reg) {
                int gm = m0 + wv16 + quad * 4 + reg;
                int gn = n0 + nt * 16 + l15;
                g[(size_t)gm * 512 + gn] = acc[nt][reg];
                pi[reg] += acc[nt][reg] * wi[nt];
                pj[reg] += acc[nt][reg] * wj[nt];
            }
        }
        #pragma unroll
        for (int mask = 1; mask < 16; mask <<= 1) {
            #pragma unroll
            for (int reg = 0; reg < 4; ++reg) {
                pi[reg] += __shfl_xor(pi[reg], mask);
                pj[reg] += __shfl_xor(pj[reg], mask);
            }
        }
        if (l15 == 0) {
            #pragma unroll
            for (int reg = 0; reg < 4; ++reg) {
                int r = m0 + wv16 + quad * 4 + reg;
                s_i[(size_t)r * 8 + head] = pi[reg];
                s_j[(size_t)r * 8 + head] = pj[reg];
            }
        }
    } else if (bx < 256) {
        // ======== edge-score role (round-10 verbatim) ========================
        {
            int c = tid & 127, halfT = tid >> 7;
            const float* we = w_attn + 128;
            #pragma unroll
            for (int hh = 0; hh < 4; ++hh) {
                int h = halfT * 4 + hh;
                float s = 0.f;
                const float* row = W_edge + (size_t)c * 512 + h * 64;
                #pragma unroll 8
                for (int f = 0; f < 64; ++f) s += row[f] * we[f];
                wvs[c * 8 + h] = s;
            }
        }
        __syncthreads();
        int e = (bx - 128) * 128 + (tid >> 1);
        int half = tid & 1;
        const float4* erow = (const float4*)(edge_attr + (size_t)e * 128 + half * 64);
        f32x4 accl = {0.f, 0.f, 0.f, 0.f};
        f32x4 acch = {0.f, 0.f, 0.f, 0.f};
        for (int c4 = 0; c4 < 16; ++c4) {
            float4 v = erow[c4];
            #pragma unroll
            for (int u = 0; u < 4; ++u) {
                int c = half * 64 + c4 * 4 + u;
                f32x4 w0 = *(const f32x4*)&wvs[c * 8];
                f32x4 w1 = *(const f32x4*)&wvs[c * 8 + 4];
                float x = (u == 0) ? v.x : (u == 1) ? v.y : (u == 2) ? v.z : v.w;
                accl += x * w0;
                acch += x * w1;
            }
        }
        #pragma unroll
        for (int q = 0; q < 4; ++q) {
            accl[q] += __shfl_xor(accl[q], 1);
            acch[q] += __shfl_xor(acch[q], 1);
        }
        if (half == 0) {
            *(f32x4*)(s_e + (size_t)e * 8)     = accl;
            *(f32x4*)(s_e + (size_t)e * 8 + 4) = acch;
        }
    } else {
        // ================= row_start role (round-11 verbatim) ================
        int b = bx - 256;
        if (tid < 64) {
            const float* row = adj + (size_t)b * 4096 + (size_t)tid * 64;
            int cnt = 0;
            #pragma unroll 8
            for (int j = 0; j < 64; ++j) cnt += (row[j] > 0.5f) ? 1 : 0;
            int inc = cnt;
            #pragma unroll
            for (int d = 1; d < 64; d <<= 1) {
                int u = __shfl_up(inc, d, 64);
                if (tid >= d) inc += u;
            }
            row_start[b * 64 + tid] = inc - cnt;
        }
    }
}

// ---------------------------------------------------------------------------
// attn round-13: one row-unit per WAVE. 256 blocks x 4 waves = 1024 units.
// ZERO __syncthreads: each wave uses only its own LDS region, and wave64
// lockstep + compiler lgkmcnt ordering make write->read within one wave safe.
// All shuffle trees / exp / div / k-ascending PV identical to round-8 attn
// -> bitwise-identical output.
// ---------------------------------------------------------------------------
__global__ __launch_bounds__(256)
void attn_kernel(const float* __restrict__ g,          // [1024][512] fp32
                 const float* __restrict__ adj,        // [16][64][64]
                 const float* __restrict__ s_e,        // [16384][8]
                 const float* __restrict__ s_i,        // [1024][8]
                 const float* __restrict__ s_j,        // [1024][8]
                 const int*   __restrict__ row_start,  // [1024]
                 float* __restrict__ out)              // [1024][512]
{
    __shared__ int   nbr_s[4][16];
    __shared__ float a_s[4][16][8];

    int tid = threadIdx.x;
    int wave = tid >> 6, lane = tid & 63;
    int bi = blockIdx.x * 4 + wave;
    int b = bi >> 6, i = bi & 63;

    // ---- neighbor extraction (wave-local) ----------------------------------
    float av = adj[(size_t)b * 4096 + (size_t)i * 64 + lane];
    unsigned long long m = __ballot(av > 0.5f);
    int m_nb = __popcll(m); m_nb = (m_nb > 16) ? 16 : m_nb;
    int before = __popcll(m & ((1ull << lane) - 1ull));

    if (lane < 16) nbr_s[wave][lane] = 0;            // default for k >= m_nb
    if (av > 0.5f && before < 16) nbr_s[wave][before] = lane;

    // ---- scores + softmax: lane = (k = lane&15, h0 = lane>>4); heads h0,h0+4
    {
        int k = lane & 15, h0 = lane >> 4;
        int nk = nbr_s[wave][k];
        float v0, v1;
        if (k < m_nb) {
            int rs = row_start[bi];
            float se0 = s_e[(size_t)(b * 1024 + rs + k) * 8 + h0];
            float se1 = s_e[(size_t)(b * 1024 + rs + k) * 8 + h0 + 4];
            float sj0 = s_j[(size_t)(b * 64 + nk) * 8 + h0];
            float sj1 = s_j[(size_t)(b * 64 + nk) * 8 + h0 + 4];
            float si0 = s_i[(size_t)bi * 8 + h0];
            float si1 = s_i[(size_t)bi * 8 + h0 + 4];
            v0 = si0 + sj0 + se0; v0 = (v0 >= 0.f) ? v0 : SLOPE * v0;
            v1 = si1 + sj1 + se1; v1 = (v1 >= 0.f) ? v1 : SLOPE * v1;
        } else {
            v0 = -1e30f; v1 = -1e30f;
        }
        float mx0 = v0, mx1 = v1;
        #pragma unroll
        for (int mask = 1; mask < 16; mask <<= 1) {
            mx0 = fmaxf(mx0, __shfl_xor(mx0, mask));
            mx1 = fmaxf(mx1, __shfl_xor(mx1, mask));
        }
        float e0 = (k < m_nb) ? __expf(v0 - mx0) : 0.f;
        float e1 = (k < m_nb) ? __expf(v1 - mx1) : 0.f;
        float s0 = e0, s1 = e1;
        #pragma unroll
        for (int mask = 1; mask < 16; mask <<= 1) {
            s0 += __shfl_xor(s0, mask);
            s1 += __shfl_xor(s1, mask);
        }
        a_s[wave][k][h0]     = e0 / s0;
        a_s[wave][k][h0 + 4] = e1 / s1;
    }
    // wave-synchronous LDS write->read within the wave's own region: safe.

    // ---- PV: lane owns 8 cols c0 = lane*8, head h = lane>>3 ----------------
    {
        int c0 = lane * 8;
        int h = lane >> 3;
        float o0 = 0.f, o1 = 0.f, o2 = 0.f, o3 = 0.f;
        float o4 = 0.f, o5 = 0.f, o6 = 0.f, o7 = 0.f;
        #pragma unroll
        for (int k = 0; k < 16; ++k) {
            float ak = a_s[wave][k][h];
            int nk = nbr_s[wave][k];
            const float4* gp = (const float4*)(g + (size_t)(b * 64 + nk) * 512 + c0);
            float4 ga = gp[0], gb = gp[1];
            o0 += ak * ga.x; o1 += ak * ga.y; o2 += ak * ga.z; o3 += ak * ga.w;
            o4 += ak * gb.x; o5 += ak * gb.y; o6 += ak * gb.z; o7 += ak * gb.w;
        }
        float4* op = (float4*)(out + (size_t)bi * 512 + c0);
        op[0] = (float4){o0, o1, o2, o3};
        op[1] = (float4){o4, o5, o6, o7};
    }
}

// ---------------------------------------------------------------------------
extern "C" void kernel_launch(void* const* d_in, const int* in_sizes, int n_in,
                              void* d_out, int out_size, void* d_ws, size_t ws_size,
                              hipStream_t stream) {
    const float* h_in      = (const float*)d_in[0];   // (16,64,1024)
    const float* adj_mat   = (const float*)d_in[1];   // (16,64,64)
    const float* edge_attr = (const float*)d_in[2];   // (16,1024,128)
    const float* W_node    = (const float*)d_in[3];   // (1024,512)
    const float* W_edge    = (const float*)d_in[4];   // (128,512)
    const float* w_attn    = (const float*)d_in[5];   // (192,)
    float* out = (float*)d_out;                       // (16,64,512) fp32

    char* ws = (char*)d_ws;
    float* g         = (float*)(ws + 0x000000);       // 2 MB
    float* s_e       = (float*)(ws + 0x200000);       // 512 KB
    float* s_i       = (float*)(ws + 0x280000);       // 32 KB
    float* s_j       = (float*)(ws + 0x288000);       // 32 KB
    int*   row_start = (int*)  (ws + 0x290000);       // 4 KB

    main_kernel<<<272, 256, 0, stream>>>(h_in, adj_mat, edge_attr,
                                         W_node, W_edge, w_attn,
                                         g, s_e, s_i, s_j, row_start);
    attn_kernel<<<256, 256, 0, stream>>>(g, adj_mat, s_e, s_i, s_j,
                                         row_start, out);
}

// Round 7
// 87.461 us; speedup vs baseline: 1.0119x; 1.0119x over previous
//
#include <hip/hip_runtime.h>
#include <hip/hip_bf16.h>
#include <stdint.h>

#define SLOPE 0.2f

typedef short s16x8 __attribute__((ext_vector_type(8)));
typedef float f32x4 __attribute__((ext_vector_type(4)));

// gfx950 native packed f32->bf16 (RNE), one VALU op for two converts.
__device__ __forceinline__ uint32_t pk_bf16(float lo, float hi) {
    uint32_t r;
    asm("v_cvt_pk_bf16_f32 %0, %1, %2" : "=v"(r) : "v"(lo), "v"(hi));
    return r;
}

// ---------------------------------------------------------------------------
// Round-14 (FINAL): exact restore of the round-4-measured best (87.50 us).
//  - main_kernel: GEMM 16 iters x K=64, distance-2 B prefetch (B global->reg
//    2 tiles ahead, reg->LDS 1 ahead, 4-slot [64][40] LDS), A regs 1 ahead.
//    Edge role 2-threads/edge on blocks 128..255; row_start on 256..271.
//  - attn_kernel: round-8 structure (1024 blocks; 4 blocks/CU TLP hides PV
//    load latency — the R6 per-wave variant measured 1-2 us SLOWER).
// Session ledger: 97.5 -> 91.4 (cvt_pk+regA+parallel softmax) -> 87.5
// (barrier halving + dist-2 prefetch). Neutral/negative: edge spread,
// K=128, per-wave attn, flag-fusion (replay-unsafe, never again).
// ---------------------------------------------------------------------------
__global__ __launch_bounds__(256)
void main_kernel(const float* __restrict__ hmat,       // [1024][1024]
                 const float* __restrict__ adj,        // [16][64][64]
                 const float* __restrict__ edge_attr,  // [16384][128]
                 const float* __restrict__ W_node,     // [1024][512]
                 const float* __restrict__ W_edge,     // [128][512]
                 const float* __restrict__ w_attn,     // [192]
                 float* __restrict__ g,                // [1024][512]
                 float* __restrict__ s_e,              // [16384][8]
                 float* __restrict__ s_i,              // [1024][8]
                 float* __restrict__ s_j,              // [1024][8]
                 int* __restrict__ row_start)          // [1024]
{
    __shared__ __align__(16) char U[20480];
    unsigned short* Bs = (unsigned short*)U;   // [4 slots][64][40] = 20480 B
    float* wvs = (float*)U;                    // edge role overlay (4 KB)

    int bx = blockIdx.x, tid = threadIdx.x;

    if (bx < 128) {
        // ================= GEMM role =========================================
        int head = bx & 7, mt = bx >> 3;
        int n0 = head * 64, m0 = mt * 64;
        int wave = tid >> 6, lane = tid & 63;
        int l15 = lane & 15, quad = lane >> 4;
        int wv16 = wave * 16;

        int kp = tid >> 4, nq = tid & 15;      // B staging (transpose)

        const float* aFrag  = hmat + (size_t)(m0 + wv16 + l15) * 1024 + quad * 8;
        const float* bpBase = W_node + (size_t)(2 * kp) * 512 + n0 + nq * 4;

        f32x4 acc[4];
        #pragma unroll
        for (int i = 0; i < 4; ++i) acc[i] = (f32x4){0.f, 0.f, 0.f, 0.f};

        float4 a0, a1, a2, a3;                 // A regs, tile `it`
        float4 b00, b01, b10, b11;             // B regs, tile `it+2` in flight

        // ---- prologue: stage tile 0 into slots 0/1; load tile-1 B regs -----
        b00 = *(const float4*)(bpBase);
        b01 = *(const float4*)(bpBase + 512);
        b10 = *(const float4*)(bpBase + 32 * 512);
        b11 = *(const float4*)(bpBase + 33 * 512);
        {
            const float* q0 = &b00.x; const float* q1 = &b01.x;
            const float* q2 = &b10.x; const float* q3 = &b11.x;
            #pragma unroll
            for (int u = 0; u < 4; ++u) {
                *(uint32_t*)&Bs[(0 * 64 + nq * 4 + u) * 40 + 2 * kp] = pk_bf16(q0[u], q1[u]);
                *(uint32_t*)&Bs[(1 * 64 + nq * 4 + u) * 40 + 2 * kp] = pk_bf16(q2[u], q3[u]);
            }
        }
        {   // B regs <- tile 1
            const float* bp = bpBase + (size_t)64 * 512;
            b00 = *(const float4*)bp;
            b01 = *(const float4*)(bp + 512);
            b10 = *(const float4*)(bp + 32 * 512);
            b11 = *(const float4*)(bp + 33 * 512);
        }
        a0 = *(const float4*)(aFrag);
        a1 = *(const float4*)(aFrag + 4);
        a2 = *(const float4*)(aFrag + 32);
        a3 = *(const float4*)(aFrag + 36);
        __syncthreads();

        // ---- main loop: 16 iters of K=64, unrolled x2 for static buf parity
        #define GITER(IT, BUF, NOT_LAST, HAS_PF2)                              \
        {                                                                      \
            union { s16x8 v; uint32_t w[4]; } A0, A1;                          \
            A0.w[0] = pk_bf16(a0.x, a0.y); A0.w[1] = pk_bf16(a0.z, a0.w);      \
            A0.w[2] = pk_bf16(a1.x, a1.y); A0.w[3] = pk_bf16(a1.z, a1.w);      \
            A1.w[0] = pk_bf16(a2.x, a2.y); A1.w[1] = pk_bf16(a2.z, a2.w);      \
            A1.w[2] = pk_bf16(a3.x, a3.y); A1.w[3] = pk_bf16(a3.z, a3.w);      \
            if (NOT_LAST) {                                                    \
                const float* ap = aFrag + ((IT) + 1) * 64;                     \
                a0 = *(const float4*)ap;        a1 = *(const float4*)(ap + 4); \
                a2 = *(const float4*)(ap + 32); a3 = *(const float4*)(ap + 36);\
            }                                                                  \
            {                                                                  \
                s16x8 af = A0.v;                                               \
                _Pragma("unroll")                                              \
                for (int nt = 0; nt < 4; ++nt) {                               \
                    s16x8 bf = *(const s16x8*)&Bs[(((BUF)*2 + 0) * 64 + nt * 16 + l15) * 40 + quad * 8]; \
                    acc[nt] = __builtin_amdgcn_mfma_f32_16x16x32_bf16(af, bf, acc[nt], 0, 0, 0); \
                }                                                              \
            }                                                                  \
            {                                                                  \
                s16x8 af = A1.v;                                               \
                _Pragma("unroll")                                              \
                for (int nt = 0; nt < 4; ++nt) {                               \
                    s16x8 bf = *(const s16x8*)&Bs[(((BUF)*2 + 1) * 64 + nt * 16 + l15) * 40 + quad * 8]; \
                    acc[nt] = __builtin_amdgcn_mfma_f32_16x16x32_bf16(af, bf, acc[nt], 0, 0, 0); \
                }                                                              \
            }                                                                  \
            if (NOT_LAST) {   /* stage tile IT+1 (regs) into slots (BUF^1)*2 */\
                int sb = ((BUF) ^ 1) * 2;                                      \
                const float* q0 = &b00.x; const float* q1 = &b01.x;            \
                const float* q2 = &b10.x; const float* q3 = &b11.x;            \
                _Pragma("unroll")                                              \
                for (int u = 0; u < 4; ++u) {                                  \
                    *(uint32_t*)&Bs[((sb + 0) * 64 + nq * 4 + u) * 40 + 2 * kp] = pk_bf16(q0[u], q1[u]); \
                    *(uint32_t*)&Bs[((sb + 1) * 64 + nq * 4 + u) * 40 + 2 * kp] = pk_bf16(q2[u], q3[u]); \
                }                                                              \
            }                                                                  \
            if (HAS_PF2) {    /* B regs <- tile IT+2 */                        \
                const float* bp = bpBase + (size_t)(((IT) + 2) * 64) * 512;    \
                b00 = *(const float4*)bp;                                      \
                b01 = *(const float4*)(bp + 512);                              \
                b10 = *(const float4*)(bp + 32 * 512);                         \
                b11 = *(const float4*)(bp + 33 * 512);                         \
            }                                                                  \
            if (NOT_LAST) __syncthreads();                                     \
        }

        for (int ii = 0; ii < 8; ++ii) {
            int it = 2 * ii;
            GITER(it,     0, true,           it + 2 < 16);
            GITER(it + 1, 1, it + 1 < 15,    it + 3 < 16);
        }
        #undef GITER

        // ============ epilogue (round-4 verbatim: g + fused s_i/s_j) =========
        float wi[4], wj[4];
        #pragma unroll
        for (int nt = 0; nt < 4; ++nt) {
            wi[nt] = w_attn[nt * 16 + l15];
            wj[nt] = w_attn[64 + nt * 16 + l15];
        }
        float pi[4], pj[4];
        #pragma unroll
        for (int reg = 0; reg < 4; ++reg) { pi[reg] = 0.f; pj[reg] = 0.f; }
        #pragma unroll
        for (int nt = 0; nt < 4; ++nt) {
            #pragma unroll
            for (int reg = 0; reg < 4; ++reg) {
                int gm = m0 + wv16 + quad * 4 + reg;
                int gn = n0 + nt * 16 + l15;
                g[(size_t)gm * 512 + gn] = acc[nt][reg];
                pi[reg] += acc[nt][reg] * wi[nt];
                pj[reg] += acc[nt][reg] * wj[nt];
            }
        }
        #pragma unroll
        for (int mask = 1; mask < 16; mask <<= 1) {
            #pragma unroll
            for (int reg = 0; reg < 4; ++reg) {
                pi[reg] += __shfl_xor(pi[reg], mask);
                pj[reg] += __shfl_xor(pj[reg], mask);
            }
        }
        if (l15 == 0) {
            #pragma unroll
            for (int reg = 0; reg < 4; ++reg) {
                int r = m0 + wv16 + quad * 4 + reg;
                s_i[(size_t)r * 8 + head] = pi[reg];
                s_j[(size_t)r * 8 + head] = pj[reg];
            }
        }
    } else if (bx < 256) {
        // ======== edge-score role: 128 blocks, 2 threads per edge row ========
        {
            int c = tid & 127, halfT = tid >> 7;
            const float* we = w_attn + 128;
            #pragma unroll
            for (int hh = 0; hh < 4; ++hh) {
                int h = halfT * 4 + hh;
                float s = 0.f;
                const float* row = W_edge + (size_t)c * 512 + h * 64;
                #pragma unroll 8
                for (int f = 0; f < 64; ++f) s += row[f] * we[f];
                wvs[c * 8 + h] = s;
            }
        }
        __syncthreads();
        int e = (bx - 128) * 128 + (tid >> 1);
        int half = tid & 1;
        const float4* erow = (const float4*)(edge_attr + (size_t)e * 128 + half * 64);
        f32x4 accl = {0.f, 0.f, 0.f, 0.f};
        f32x4 acch = {0.f, 0.f, 0.f, 0.f};
        for (int c4 = 0; c4 < 16; ++c4) {
            float4 v = erow[c4];
            #pragma unroll
            for (int u = 0; u < 4; ++u) {
                int c = half * 64 + c4 * 4 + u;
                f32x4 w0 = *(const f32x4*)&wvs[c * 8];
                f32x4 w1 = *(const f32x4*)&wvs[c * 8 + 4];
                float x = (u == 0) ? v.x : (u == 1) ? v.y : (u == 2) ? v.z : v.w;
                accl += x * w0;
                acch += x * w1;
            }
        }
        #pragma unroll
        for (int q = 0; q < 4; ++q) {
            accl[q] += __shfl_xor(accl[q], 1);
            acch[q] += __shfl_xor(acch[q], 1);
        }
        if (half == 0) {
            *(f32x4*)(s_e + (size_t)e * 8)     = accl;
            *(f32x4*)(s_e + (size_t)e * 8 + 4) = acch;
        }
    } else {
        // ================= row_start role =================
        int b = bx - 256;
        if (tid < 64) {
            const float* row = adj + (size_t)b * 4096 + (size_t)tid * 64;
            int cnt = 0;
            #pragma unroll 8
            for (int j = 0; j < 64; ++j) cnt += (row[j] > 0.5f) ? 1 : 0;
            int inc = cnt;
            #pragma unroll
            for (int d = 1; d < 64; d <<= 1) {
                int u = __shfl_up(inc, d, 64);
                if (tid >= d) inc += u;
            }
            row_start[b * 64 + tid] = inc - cnt;
        }
    }
}

// ---------------------------------------------------------------------------
// attn: one block per (b,i). Round-8 version verbatim (best measured config:
// 4 blocks/CU of TLP hides PV load latency; per-wave variant was slower).
// ---------------------------------------------------------------------------
__global__ __launch_bounds__(256)
void attn_kernel(const float* __restrict__ g,          // [1024][512] fp32
                 const float* __restrict__ adj,        // [16][64][64]
                 const float* __restrict__ s_e,        // [16384][8]
                 const float* __restrict__ s_i,        // [1024][8]
                 const float* __restrict__ s_j,        // [1024][8]
                 const int*   __restrict__ row_start,  // [1024]
                 float* __restrict__ out)              // [1024][512]
{
    __shared__ float a_s[16][8];
    __shared__ int nbr[16];
    __shared__ int m_nb_s;

    int bi = blockIdx.x;
    int b = bi >> 6, i = bi & 63;
    int tid = threadIdx.x;

    if (tid < 16) nbr[tid] = 0;          // safe default for k >= m_nb (a=0 there)
    if (tid < 64) {
        float av = adj[(size_t)b * 4096 + (size_t)i * 64 + tid];
        unsigned long long m = __ballot(av > 0.5f);
        if (av > 0.5f) {
            int before = __popcll(m & ((1ull << tid) - 1ull));
            if (before < 16) nbr[before] = tid;
        }
        if (tid == 0) {
            int c = __popcll(m);
            m_nb_s = (c > 16) ? 16 : c;
        }
    }
    __syncthreads();

    int m_nb = m_nb_s;

    int c0 = tid * 2;
    int h = tid >> 5;
    float2 gv[16];
    #pragma unroll
    for (int k = 0; k < 16; ++k) {
        gv[k] = *(const float2*)(g + (size_t)(b * 64 + nbr[k]) * 512 + c0);
    }

    if (tid < 128) {
        int hh = tid >> 4, k = tid & 15;
        float v;
        if (k < m_nb) {
            int rs = row_start[bi];
            float se = s_e[(size_t)(b * 1024 + rs + k) * 8 + hh];
            float sj = s_j[(size_t)(b * 64 + nbr[k]) * 8 + hh];
            float si = s_i[(size_t)bi * 8 + hh];
            v = si + sj + se;
            v = (v >= 0.f) ? v : SLOPE * v;
        } else {
            v = -1e30f;
        }
        float mx = v;
        #pragma unroll
        for (int mask = 1; mask < 16; mask <<= 1)
            mx = fmaxf(mx, __shfl_xor(mx, mask));
        float e = (k < m_nb) ? __expf(v - mx) : 0.f;
        float ssum = e;
        #pragma unroll
        for (int mask = 1; mask < 16; mask <<= 1)
            ssum += __shfl_xor(ssum, mask);
        a_s[k][hh] = e / ssum;
    }
    __syncthreads();

    float o0 = 0.f, o1 = 0.f;
    #pragma unroll
    for (int k = 0; k < 16; ++k) {
        float ak = a_s[k][h];
        o0 += ak * gv[k].x;
        o1 += ak * gv[k].y;
    }
    out[(size_t)bi * 512 + c0]     = o0;
    out[(size_t)bi * 512 + c0 + 1] = o1;
}

// ---------------------------------------------------------------------------
extern "C" void kernel_launch(void* const* d_in, const int* in_sizes, int n_in,
                              void* d_out, int out_size, void* d_ws, size_t ws_size,
                              hipStream_t stream) {
    const float* h_in      = (const float*)d_in[0];   // (16,64,1024)
    const float* adj_mat   = (const float*)d_in[1];   // (16,64,64)
    const float* edge_attr = (const float*)d_in[2];   // (16,1024,128)
    const float* W_node    = (const float*)d_in[3];   // (1024,512)
    const float* W_edge    = (const float*)d_in[4];   // (128,512)
    const float* w_attn    = (const float*)d_in[5];   // (192,)
    float* out = (float*)d_out;                       // (16,64,512) fp32

    char* ws = (char*)d_ws;
    float* g         = (float*)(ws + 0x000000);       // 2 MB
    float* s_e       = (float*)(ws + 0x200000);       // 512 KB
    float* s_i       = (float*)(ws + 0x280000);       // 32 KB
    float* s_j       = (float*)(ws + 0x288000);       // 32 KB
    int*   row_start = (int*)  (ws + 0x290000);       // 4 KB

    main_kernel<<<272, 256, 0, stream>>>(h_in, adj_mat, edge_attr,
                                         W_node, W_edge, w_attn,
                                         g, s_e, s_i, s_j, row_start);
    attn_kernel<<<1024, 256, 0, stream>>>(g, adj_mat, s_e, s_i, s_j,
                                          row_start, out);
}